// Round 6
// baseline (309.113 us; speedup 1.0000x reference)
//
#include <hip/hip_runtime.h>
#include <hip/hip_cooperative_groups.h>
#include <math.h>

namespace cg = cooperative_groups;

#define B_   8
#define CIN  256
#define L_   1024
#define NH_  8
#define DH_  32

typedef __attribute__((ext_vector_type(8))) short short8;
typedef __attribute__((ext_vector_type(4))) short short4v;
typedef __attribute__((ext_vector_type(4))) float f32x4;
typedef __attribute__((ext_vector_type(4))) unsigned int uint4v;
typedef __attribute__((ext_vector_type(2))) unsigned int uint2v;

__device__ inline short f2bf_hu(float f) {       // bf16 half-up, 2 ops
    union { float f; unsigned u; } v; v.f = f;
    return (short)((v.u + 0x8000u) >> 16);
}
// pack bf16(a) | bf16(b)<<16 : 2 adds + 1 v_perm
__device__ inline unsigned pkbf2(float a, float b) {
    union { float f; unsigned u; } x, y; x.f = a; y.f = b;
    return __builtin_amdgcn_perm(y.u + 0x8000u, x.u + 0x8000u, 0x07060302u);
}

// ===========================================================================
// Single cooperative kernel: QKV-GEMM -> grid.sync -> flash-attn ->
// grid.sync -> proj-GEMM(+bias+residual). Phases 1/3 are LDS-free
// (direct fragment gather); phase 2 is the validated round-5 attention.
// Block-stride item loops make any grid size correct; target 1024 (4/CU).
// ===========================================================================
__global__ __launch_bounds__(256, 4) void mega(
    const float* __restrict__ x,      const float* __restrict__ w_qkv,
    const float* __restrict__ b_qkv,  const float* __restrict__ w_proj,
    const float* __restrict__ b_proj, float* __restrict__ out,
    short* __restrict__ qkvT,         short* __restrict__ attnoT)
{
    // LDS only used by phase 2 (23 KB)
    __shared__ short Ks[64][40];
    __shared__ short Vt[48][80];
    __shared__ __align__(16) char umem[64 * 80 * 2];
    short (*Ss)[80]  = (short(*)[80])umem;          // [i][j] bf16 P
    float (*OtT)[38] = (float(*)[38])umem;          // [i][dv] fp32 epilogue

    cg::grid_group grid = cg::this_grid();
    const int t = threadIdx.x, lane = t & 63, wv = t >> 6;
    const int n = lane & 15, quad = lane >> 4;
    const int nblk = gridDim.x;

    // --------------- Phase 1: qkvT[b][l][o] = x·w_qkv + bias (bf16) --------
    // Tile 64(l) x 96(o); A gathered from x[c][l] fp32, B packed from w rows.
    for (int it = blockIdx.x; it < 1024; it += nblk) {
        const int b = it >> 7, r = it & 127;
        const int o0 = (r >> 4) * 96, l0 = (r & 15) * 64;

        f32x4 acc[6];
        #pragma unroll
        for (int nf = 0; nf < 6; nf++) acc[nf] = (f32x4){0.f, 0.f, 0.f, 0.f};

        for (int c0 = 0; c0 < CIN; c0 += 32) {
            const float* xp = x + (((size_t)(b * CIN + c0 + quad * 8)) << 10)
                                + l0 + wv * 16 + n;
            short8 af;
            #pragma unroll
            for (int u = 0; u < 8; u++) af[u] = f2bf_hu(xp[(size_t)u << 10]);

            #pragma unroll
            for (int nf = 0; nf < 6; nf++) {
                const float* wp = w_qkv + (size_t)(o0 + nf * 16 + n) * CIN + c0 + quad * 8;
                const float4 w0 = *(const float4*)wp;
                const float4 w1 = *(const float4*)(wp + 4);
                union { uint4v u; short8 s; } bfu;
                bfu.u = (uint4v){ pkbf2(w0.x, w0.y), pkbf2(w0.z, w0.w),
                                  pkbf2(w1.x, w1.y), pkbf2(w1.z, w1.w) };
                acc[nf] = __builtin_amdgcn_mfma_f32_16x16x32_bf16(af, bfu.s, acc[nf], 0, 0, 0);
            }
        }
        #pragma unroll
        for (int nf = 0; nf < 6; nf++) {
            const int o = o0 + nf * 16 + n;
            const float bi = b_qkv[o];
            #pragma unroll
            for (int reg = 0; reg < 4; reg++) {
                const size_t l = l0 + wv * 16 + quad * 4 + reg;
                qkvT[(((size_t)b << 10) + l) * 768 + o] = f2bf_hu(acc[nf][reg] + bi);
            }
        }
    }

    grid.sync();

    // --------------- Phase 2: flash attention (round-5 validated) ----------
    // ones row (dv=32) + zero rows 33..47; invariant across items
    for (int idx = t; idx < 16 * 80; idx += 256) {
        const int rr = idx / 80, c = idx - rr * 80;
        Vt[32 + rr][c] = (rr == 0) ? (short)0x3F80 : (short)0;
    }

    const float K1 = 0.25503510f;    // (1/sqrt(32)) * log2(e)
    const float K2 = 11.54156036f;   // 8 * log2(e)

    for (int it = blockIdx.x; it < 1024; it += nblk) {
        const int b = it >> 7, h = (it >> 4) & 7, i0 = (it & 15) * 64;
        const short* base = qkvT + (((size_t)b << 10)) * 768;

        const short8 qa = *(const short8*)&base[(size_t)(i0 + wv * 16 + n) * 768
                                                + h * DH_ + quad * 8];
        f32x4 o_acc[3];
        #pragma unroll
        for (int nf = 0; nf < 3; nf++) o_acc[nf] = (f32x4){0.f, 0.f, 0.f, 0.f};

        for (int j0 = 0; j0 < L_; j0 += 64) {
            __syncthreads();
            {   // K stage: straight 16B row copies
                const int j = t >> 2, cs = (t & 3) * 8;
                *(uint4v*)&Ks[j][cs] =
                    *(const uint4v*)&base[(size_t)(j0 + j) * 768 + 256 + h * DH_ + cs];
            }
            #pragma unroll
            for (int rr = 0; rr < 2; rr++) {   // V stage: swizzled transpose
                const int idx = t + rr * 256;
                const int j = idx >> 3, ds = (idx & 7) * 4;
                const short4v v4 = *(const short4v*)&base[(size_t)(j0 + j) * 768
                                                          + 512 + h * DH_ + ds];
                #pragma unroll
                for (int u = 0; u < 4; u++) {
                    const int dv = ds + u;
                    Vt[dv][j ^ (((dv >> 2) & 7) << 3)] = v4[u];
                }
            }
            __syncthreads();

            // S^T = K Q^T : lane holds S[i = wv*16+n][j = f*16+quad*4+r]
            #pragma unroll
            for (int f = 0; f < 4; f++) {
                const short8 kf = *(const short8*)&Ks[f * 16 + n][quad * 8];
                f32x4 z = {0.f, 0.f, 0.f, 0.f};
                const f32x4 s = __builtin_amdgcn_mfma_f32_16x16x32_bf16(kf, qa, z, 0, 0, 0);
                const float p0 = exp2f(fmaf(s[0], K1, -K2));
                const float p1 = exp2f(fmaf(s[1], K1, -K2));
                const float p2 = exp2f(fmaf(s[2], K1, -K2));
                const float p3 = exp2f(fmaf(s[3], K1, -K2));
                uint2v pk = { pkbf2(p0, p1), pkbf2(p2, p3) };
                *(uint2v*)&Ss[wv * 16 + n][f * 16 + quad * 4] = pk;
            }
            // wave-private Ss rows: in-wave lgkmcnt ordering, no barrier

            // O += P V  (nf=2 = ones column -> denominator)
            #pragma unroll
            for (int kk = 0; kk < 2; kk++) {
                const short8 pf = *(const short8*)&Ss[wv * 16 + n][kk * 32 + quad * 8];
                #pragma unroll
                for (int nf = 0; nf < 3; nf++) {
                    const int dv = nf * 16 + n;
                    const int msk = ((dv >> 2) & 7) << 3;
                    const short8 vf = *(const short8*)&Vt[dv][(kk * 32 + quad * 8) ^ msk];
                    o_acc[nf] = __builtin_amdgcn_mfma_f32_16x16x32_bf16(pf, vf, o_acc[nf], 0, 0, 0);
                }
            }
        }

        __syncthreads();   // all PV reads of Ss done before OtT overwrites umem
        #pragma unroll
        for (int rr = 0; rr < 4; rr++) {
            const float lv  = __shfl(o_acc[2][rr], lane & 48, 64);
            const float inv = 1.f / lv;
            const int il = wv * 16 + quad * 4 + rr;
            OtT[il][n]      = o_acc[0][rr] * inv;
            OtT[il][16 + n] = o_acc[1][rr] * inv;
        }
        __syncthreads();
        short* ob = attnoT + ((((size_t)b << 10)) + i0) * CIN + h * DH_;
        #pragma unroll
        for (int rr = 0; rr < 2; rr++) {
            const int idx = t + rr * 256;
            const int l = idx >> 3, cs = (idx & 7) * 4;
            uint2v pv;
            pv.x = pkbf2(OtT[l][cs],     OtT[l][cs + 1]);
            pv.y = pkbf2(OtT[l][cs + 2], OtT[l][cs + 3]);
            *(uint2v*)&ob[(size_t)l * CIN + cs] = pv;
        }
    }

    grid.sync();

    // --------------- Phase 3: out = w_proj·attnT + bias + x ----------------
    // Tile 64(o) x 32(l); LDS-free: A packed from w_proj, B direct bf16 16B.
    for (int it = blockIdx.x; it < 1024; it += nblk) {
        const int b = it >> 7, r = it & 127;
        const int o0 = (r >> 5) * 64, l0 = (r & 31) * 32;

        f32x4 acc[2];
        #pragma unroll
        for (int nf = 0; nf < 2; nf++) acc[nf] = (f32x4){0.f, 0.f, 0.f, 0.f};

        for (int c0 = 0; c0 < CIN; c0 += 32) {
            const float* wp = w_proj + (size_t)(o0 + wv * 16 + n) * CIN + c0 + quad * 8;
            const float4 w0 = *(const float4*)wp;
            const float4 w1 = *(const float4*)(wp + 4);
            union { uint4v u; short8 s; } afu;
            afu.u = (uint4v){ pkbf2(w0.x, w0.y), pkbf2(w0.z, w0.w),
                              pkbf2(w1.x, w1.y), pkbf2(w1.z, w1.w) };
            #pragma unroll
            for (int nf = 0; nf < 2; nf++) {
                const short8 bf = *(const short8*)&attnoT[
                    (((size_t)b << 10) + l0 + nf * 16 + n) * CIN + c0 + quad * 8];
                acc[nf] = __builtin_amdgcn_mfma_f32_16x16x32_bf16(afu.s, bf, acc[nf], 0, 0, 0);
            }
        }
        #pragma unroll
        for (int reg = 0; reg < 4; reg++) {
            const int o = o0 + wv * 16 + quad * 4 + reg;
            const float bi = b_proj[o];
            #pragma unroll
            for (int nf = 0; nf < 2; nf++) {
                const size_t off = (((size_t)b * CIN + o) << 10) + l0 + nf * 16 + n;
                out[off] = acc[nf][reg] + bi + x[off];
            }
        }
    }
}

// ---------------------------------------------------------------------------
extern "C" void kernel_launch(void* const* d_in, const int* in_sizes, int n_in,
                              void* d_out, int out_size, void* d_ws, size_t ws_size,
                              hipStream_t stream) {
    const float* x      = (const float*)d_in[0];
    const float* w_qkv  = (const float*)d_in[1];
    const float* b_qkv  = (const float*)d_in[2];
    const float* w_proj = (const float*)d_in[3];
    const float* b_proj = (const float*)d_in[4];
    float* outp = (float*)d_out;

    short* qkvT   = (short*)d_ws;                          // 12 MB [b][l][768]
    short* attnoT = qkvT + (size_t)B_ * L_ * 768;          // 4 MB  [b][l][256]

    int occ = 0;
    hipOccupancyMaxActiveBlocksPerMultiprocessor(&occ, mega, 256, 0);
    if (occ < 1) occ = 1;
    unsigned int nblk = (unsigned int)occ * 256u;
    if (nblk > 1024u) nblk = 1024u;

    void* args[] = { (void*)&x, (void*)&w_qkv, (void*)&b_qkv, (void*)&w_proj,
                     (void*)&b_proj, (void*)&outp, (void*)&qkvT, (void*)&attnoT };
    hipLaunchCooperativeKernel((const void*)mega, dim3(nblk), dim3(256),
                               args, 0, stream);
}

// Round 7
// 129.570 us; speedup vs baseline: 2.3857x; 2.3857x over previous
//
#include <hip/hip_runtime.h>
#include <math.h>

#define B_   8
#define CIN  256
#define L_   1024
#define NH_  8
#define DH_  32

typedef __attribute__((ext_vector_type(8))) short short8;
typedef __attribute__((ext_vector_type(4))) short short4v;
typedef __attribute__((ext_vector_type(4))) float f32x4;
typedef __attribute__((ext_vector_type(4))) unsigned int uint4v;
typedef __attribute__((ext_vector_type(2))) unsigned int uint2v;

__device__ inline short f2bf_hu(float f) {       // bf16 half-up, 2 ops
    union { float f; unsigned u; } v; v.f = f;
    return (short)((v.u + 0x8000u) >> 16);
}
// pack bf16(a) | bf16(b)<<16 : 2 adds + 1 v_perm
__device__ inline unsigned pkbf2(float a, float b) {
    union { float f; unsigned u; } x, y; x.f = a; y.f = b;
    return __builtin_amdgcn_perm(y.u + 0x8000u, x.u + 0x8000u, 0x07060302u);
}

// ---------------------------------------------------------------------------
// QKV GEMM with fused transpose+cast of x.
// qkvT[b][l][o] = x[b][:,l]·w_qkv[o][:] + bias[o], bf16 out, [l][o] layout.
// X staged from fp32 [c][l] with XOR slot swizzle: value of channel c for
// row l lives at col ((c>>3)^(l&3))*8 + (c&7); read undoes it per-row.
// Tile 64(l) x 128(o), K=32. Grid 16x6x8 = 768 blocks = 3/CU exact.
// ---------------------------------------------------------------------------
__global__ __launch_bounds__(256) void qkv_gemm(
    const float* __restrict__ x, const float* __restrict__ w,
    const float* __restrict__ bias, short* __restrict__ qkvT)
{
    __shared__ short Xs[64][40];
    __shared__ short Wt[128][40];
    const int t = threadIdx.x, lane = t & 63, wv = t >> 6;
    const int n = lane & 15, quad = lane >> 4;
    const int b = blockIdx.z, o0 = blockIdx.y * 128, l0 = blockIdx.x * 64;

    float bias_r[8];
    #pragma unroll
    for (int nf = 0; nf < 8; nf++) bias_r[nf] = bias[o0 + nf * 16 + n];

    f32x4 acc[8];
    #pragma unroll
    for (int nf = 0; nf < 8; nf++) acc[nf] = (f32x4){0.f, 0.f, 0.f, 0.f};

    const int cS = t >> 3, lsS = (t & 7) * 8;       // X stage roles
    const int rslot = ((cS >> 3) << 3) | (cS & 7);  // c decomposed

    for (int c0 = 0; c0 < CIN; c0 += 32) {
        {   // X stage: 32c x 64l fp32, coalesced along l; transposed swizzled write
            const float* xp = &x[(((size_t)b * CIN + c0 + cS) << 10) + l0 + lsS];
            const float4 xa = *(const float4*)xp;
            const float4 xb = *(const float4*)(xp + 4);
            const float vals[8] = {xa.x, xa.y, xa.z, xa.w, xb.x, xb.y, xb.z, xb.w};
            #pragma unroll
            for (int k = 0; k < 8; k++) {
                const int l = lsS + k;
                const int col = (((cS >> 3) ^ (l & 3)) << 3) | (cS & 7);
                Xs[l][col] = f2bf_hu(vals[k]);
            }
        }
        {   // W tile: 128x32, fp32 -> bf16 packed, b128 writes
            const int o = t >> 1, cs = (t & 1) * 16;
            const float* wp = &w[(size_t)(o0 + o) * CIN + c0 + cs];
            const float4 w0 = *(const float4*)(wp);
            const float4 w1 = *(const float4*)(wp + 4);
            const float4 w2 = *(const float4*)(wp + 8);
            const float4 w3 = *(const float4*)(wp + 12);
            uint4v pa = { pkbf2(w0.x, w0.y), pkbf2(w0.z, w0.w),
                          pkbf2(w1.x, w1.y), pkbf2(w1.z, w1.w) };
            uint4v pb = { pkbf2(w2.x, w2.y), pkbf2(w2.z, w2.w),
                          pkbf2(w3.x, w3.y), pkbf2(w3.z, w3.w) };
            *(uint4v*)&Wt[o][cs]     = pa;
            *(uint4v*)&Wt[o][cs + 8] = pb;
        }
        __syncthreads();

        const int arow = wv * 16 + n;
        const short8 af = *(const short8*)&Xs[arow][(quad ^ (arow & 3)) * 8];
        #pragma unroll
        for (int nf = 0; nf < 8; nf++) {
            const short8 bf = *(const short8*)&Wt[nf * 16 + n][quad * 8];
            acc[nf] = __builtin_amdgcn_mfma_f32_16x16x32_bf16(af, bf, acc[nf], 0, 0, 0);
        }
        __syncthreads();
    }

    #pragma unroll
    for (int reg = 0; reg < 4; reg++) {
        const size_t l = l0 + wv * 16 + quad * 4 + reg;
        short* row = qkvT + (((size_t)b << 10) + l) * 768 + o0 + n;
        #pragma unroll
        for (int nf = 0; nf < 8; nf++)
            row[nf * 16] = f2bf_hu(acc[nf][reg] + bias_r[nf]);
    }
}

// ---------------------------------------------------------------------------
// Proj GEMM: out[b][o][l] = w[o][:]·aT[b][l][:] + bias[o] + resid[b][o][l]
// Tile 64(o) x 64(l). Grid 16x4x8 = 512 blocks = 2/CU exact. (round-5)
// ---------------------------------------------------------------------------
__global__ __launch_bounds__(256) void proj_gemm(
    const short* __restrict__ aT, const float* __restrict__ w,
    const float* __restrict__ bias, const float* __restrict__ resid,
    float* __restrict__ out)
{
    __shared__ short Xs[64][40];
    __shared__ short Wt[64][40];
    const int t = threadIdx.x, lane = t & 63, wv = t >> 6;
    const int n = lane & 15, quad = lane >> 4;
    const int b = blockIdx.z, o0 = blockIdx.y * 64, l0 = blockIdx.x * 64;

    float bias_r[4];
    #pragma unroll
    for (int reg = 0; reg < 4; reg++) bias_r[reg] = bias[o0 + wv * 16 + quad * 4 + reg];

    f32x4 acc[4];
    #pragma unroll
    for (int nf = 0; nf < 4; nf++) acc[nf] = (f32x4){0.f, 0.f, 0.f, 0.f};

    for (int c0 = 0; c0 < CIN; c0 += 32) {
        {   // aT tile 64x32 bf16
            const int l = t >> 2, cs = (t & 3) * 8;
            *(uint4v*)&Xs[l][cs] =
                *(const uint4v*)&aT[(((size_t)b << 10) + l0 + l) * CIN + c0 + cs];
        }
        {   // W tile 64x32, 8 floats per thread
            const int o = t >> 2, cs = (t & 3) * 8;
            const float* wp = &w[(size_t)(o0 + o) * CIN + c0 + cs];
            const float4 a4 = *(const float4*)(wp);
            const float4 b4 = *(const float4*)(wp + 4);
            uint4v pw = { pkbf2(a4.x, a4.y), pkbf2(a4.z, a4.w),
                          pkbf2(b4.x, b4.y), pkbf2(b4.z, b4.w) };
            *(uint4v*)&Wt[o][cs] = pw;
        }
        __syncthreads();

        const short8 af = *(const short8*)&Wt[wv * 16 + n][quad * 8];
        #pragma unroll
        for (int nf = 0; nf < 4; nf++) {
            const short8 bf = *(const short8*)&Xs[nf * 16 + n][quad * 8];
            acc[nf] = __builtin_amdgcn_mfma_f32_16x16x32_bf16(af, bf, acc[nf], 0, 0, 0);
        }
        __syncthreads();
    }

    #pragma unroll
    for (int reg = 0; reg < 4; reg++) {
        const int o = o0 + wv * 16 + quad * 4 + reg;
        #pragma unroll
        for (int nf = 0; nf < 4; nf++) {
            const size_t off = (((size_t)b * CIN + o) << 10) + l0 + nf * 16 + n;
            out[off] = acc[nf][reg] + bias_r[reg] + resid[off];
        }
    }
}

// ---------------------------------------------------------------------------
// Flash attention v3: fixed-shift softmax, S^T-MFMA.
//  - K fragments DIRECT from global (qkvT is [l][d], k-contiguous),
//    software-pipelined one j-tile ahead.
//  - V double-buffered in LDS -> ONE barrier per tile.
//  - ones-column vf is a register constant (no LDS rows/reads for it).
//  - Ss row stride 88 shorts: P write/read conflicts 4-way -> 2-way (free).
// ---------------------------------------------------------------------------
__global__ __launch_bounds__(256) void attn_mfma(
    const short* __restrict__ qkvT, short* __restrict__ attnoT)
{
    __shared__ short Vt[2][32][80];                // swizzled: col ^= ((dv>>2)&7)<<3
    __shared__ __align__(16) char umem[64 * 88 * 2];
    short (*Ss)[88] = (short(*)[88])umem;          // [i][j] bf16 P
    float (*OtT)[38] = (float(*)[38])umem;         // [i][dv] fp32 epilogue

    const int t = threadIdx.x, lane = t & 63, wv = t >> 6;
    const int n = lane & 15, quad = lane >> 4;
    const int b = blockIdx.z, h = blockIdx.y, i0 = blockIdx.x * 64;

    const short* base = qkvT + ((size_t)b << 10) * 768;
    const short* kbase = base + 256 + h * DH_;
    const short* vbase = base + 512 + h * DH_;

    // Q A-frag direct from global
    const short8 qa = *(const short8*)&base[(size_t)(i0 + wv * 16 + n) * 768 + h * DH_ + quad * 8];

    // constant ones-column B-frag: B[k][n]=1 iff n==0 (dv==32)
    short8 vf2;
    {
        const short one = (n == 0) ? (short)0x3F80 : (short)0;
        #pragma unroll
        for (int u = 0; u < 8; u++) vf2[u] = one;
    }

    f32x4 o_acc[3];
    #pragma unroll
    for (int nf = 0; nf < 3; nf++) o_acc[nf] = (f32x4){0.f, 0.f, 0.f, 0.f};

    const float K1 = 0.25503510f;    // (1/sqrt(32)) * log2(e)
    const float K2 = 11.54156036f;   // 8 * log2(e)

    // staging roles
    const int jS = t >> 3, dsS = (t & 7) * 4;      // V stage (x2 with +32)

    // ---- prologue: stage V tile0 into buf0, load K frags tile0 ----
    #pragma unroll
    for (int rr = 0; rr < 2; rr++) {
        const int j = jS + rr * 32;
        const short4v v4 = *(const short4v*)&vbase[(size_t)j * 768 + dsS];
        #pragma unroll
        for (int u = 0; u < 4; u++) {
            const int dv = dsS + u;
            Vt[0][dv][j ^ (((dv >> 2) & 7) << 3)] = v4[u];
        }
    }
    short8 kf[4];
    #pragma unroll
    for (int f = 0; f < 4; f++)
        kf[f] = *(const short8*)&kbase[(size_t)(f * 16 + n) * 768 + quad * 8];

    for (int it = 0; it < 16; it++) {
        const int cur = it & 1;
        __syncthreads();   // prev iter's reads of buf cur done; buf cur writes visible

        short8 kf_n[4];
        if (it < 15) {     // stage tile it+1: V into buf cur^1, K into regs
            const int j0n = (it + 1) * 64;
            #pragma unroll
            for (int rr = 0; rr < 2; rr++) {
                const int j = jS + rr * 32;
                const short4v v4 = *(const short4v*)&vbase[(size_t)(j0n + j) * 768 + dsS];
                #pragma unroll
                for (int u = 0; u < 4; u++) {
                    const int dv = dsS + u;
                    Vt[cur ^ 1][dv][j ^ (((dv >> 2) & 7) << 3)] = v4[u];
                }
            }
            #pragma unroll
            for (int f = 0; f < 4; f++)
                kf_n[f] = *(const short8*)&kbase[(size_t)(j0n + f * 16 + n) * 768 + quad * 8];
        }

        // ---- S^T = K Q^T : lane holds S[i=wv*16+n][j=f*16+quad*4+r] ----
        #pragma unroll
        for (int f = 0; f < 4; f++) {
            f32x4 z = {0.f, 0.f, 0.f, 0.f};
            const f32x4 s = __builtin_amdgcn_mfma_f32_16x16x32_bf16(kf[f], qa, z, 0, 0, 0);
            const float p0 = exp2f(fmaf(s[0], K1, -K2));
            const float p1 = exp2f(fmaf(s[1], K1, -K2));
            const float p2 = exp2f(fmaf(s[2], K1, -K2));
            const float p3 = exp2f(fmaf(s[3], K1, -K2));
            uint2v pk = { pkbf2(p0, p1), pkbf2(p2, p3) };
            *(uint2v*)&Ss[wv * 16 + n][f * 16 + quad * 4] = pk;
        }
        // wave-private Ss rows: in-wave lgkmcnt ordering, no barrier

        // ---- O += P V (vf2 = register ones-column -> denominator) ----
        #pragma unroll
        for (int kk = 0; kk < 2; kk++) {
            const short8 pf = *(const short8*)&Ss[wv * 16 + n][kk * 32 + quad * 8];
            #pragma unroll
            for (int nf = 0; nf < 2; nf++) {
                const int dv = nf * 16 + n;
                const int msk = ((dv >> 2) & 7) << 3;
                const short8 vf = *(const short8*)&Vt[cur][dv][(kk * 32 + quad * 8) ^ msk];
                o_acc[nf] = __builtin_amdgcn_mfma_f32_16x16x32_bf16(pf, vf, o_acc[nf], 0, 0, 0);
            }
            o_acc[2] = __builtin_amdgcn_mfma_f32_16x16x32_bf16(pf, vf2, o_acc[2], 0, 0, 0);
        }

        #pragma unroll
        for (int f = 0; f < 4; f++) kf[f] = kf_n[f];
    }

    __syncthreads();   // all PV reads of Ss done before OtT overwrites umem
    #pragma unroll
    for (int r = 0; r < 4; r++) {
        const float lv  = __shfl(o_acc[2][r], lane & 48, 64);
        const float inv = 1.f / lv;
        const int il = wv * 16 + quad * 4 + r;
        OtT[il][n]      = o_acc[0][r] * inv;
        OtT[il][16 + n] = o_acc[1][r] * inv;
    }
    __syncthreads();
    short* ob = attnoT + (((size_t)b << 10) + i0) * CIN + h * DH_;
    #pragma unroll
    for (int r = 0; r < 2; r++) {
        const int idx = t + r * 256;
        const int l = idx >> 3, cs = (idx & 7) * 4;
        uint2v pv;
        pv.x = pkbf2(OtT[l][cs],     OtT[l][cs + 1]);
        pv.y = pkbf2(OtT[l][cs + 2], OtT[l][cs + 3]);
        *(uint2v*)&ob[(size_t)l * CIN + cs] = pv;
    }
}

// ---------------------------------------------------------------------------
extern "C" void kernel_launch(void* const* d_in, const int* in_sizes, int n_in,
                              void* d_out, int out_size, void* d_ws, size_t ws_size,
                              hipStream_t stream) {
    const float* x      = (const float*)d_in[0];
    const float* w_qkv  = (const float*)d_in[1];
    const float* b_qkv  = (const float*)d_in[2];
    const float* w_proj = (const float*)d_in[3];
    const float* b_proj = (const float*)d_in[4];
    float* out = (float*)d_out;

    short* qkvT   = (short*)d_ws;                          // 12 MB [b][l][768]
    short* attnoT = qkvT + (size_t)B_ * L_ * 768;          // 4 MB  [b][l][256]

    qkv_gemm<<<dim3(16, 6, B_), 256, 0, stream>>>(x, w_qkv, b_qkv, qkvT);
    attn_mfma<<<dim3(16, NH_, B_), 256, 0, stream>>>(qkvT, attnoT);
    proj_gemm<<<dim3(16, 4, B_), 256, 0, stream>>>(attnoT, w_proj, b_proj, x, out);
}